// Round 2
// baseline (5690.322 us; speedup 1.0000x reference)
//
#include <hip/hip_runtime.h>
#include <math.h>

#define LRELU(x) ((x) >= 0.f ? (x) : 0.2f*(x))

// ---- static device scratch: avoids any dependence on ws_size (suspected
// cause of round-1 memory fault: our layout needs ~272 MB of scratch). ----
#define WS_FLOATS 71303168u   // 285 MB
__device__ __align__(256) float g_ws[WS_FLOATS];

// ---------------- transpose (B,3,N) -> (B*N,3) ----------------
__global__ __launch_bounds__(256) void k_transpose_in(const float* __restrict__ data,
                                                      float* __restrict__ x0) {
    int i = blockIdx.x*256 + threadIdx.x;      // over B*N = 32768
    int b = i >> 11, n = i & 2047;
    #pragma unroll
    for (int c = 0; c < 3; c++)
        x0[(long)i*3 + c] = data[((long)b*3 + c)*2048 + n];
}

// ---------------- squared norms ----------------
__global__ __launch_bounds__(256) void k_sqnorm(const float* __restrict__ x,
                                                float* __restrict__ sq, int C) {
    int i = blockIdx.x*256 + threadIdx.x;      // over 32768 points
    const float* xr = x + (long)i*C;
    float s = 0.f;
    for (int c = 0; c < C; c++) s = fmaf(xr[c], xr[c], s);
    sq[i] = s;
}

// ---------------- generic fp32 GEMM: C[i,j] (op)= sum_k A[i,k]*B[j,k] ----------------
// mode 0: store, mode 1: accumulate (+=), mode 2: dist epilogue 2*acc - sq[i] - sq[j]
#define KC 8
__global__ __launch_bounds__(256) void k_gemm_nt(
    const float* __restrict__ A, int lda, long sAb,
    const float* __restrict__ B, int ldb, long sBb,
    float* __restrict__ Cm, int ldc, long sCb,
    int K, int Nj, int mode, const float* __restrict__ sq, int sqStride)
{
    __shared__ float As[KC][132];
    __shared__ float Bs[KC][132];
    int z = blockIdx.z;
    const float* Ab = A + (long)z*sAb;
    const float* Bb = B + (long)z*sBb;
    float* Cb = Cm + (long)z*sCb;
    int rowBase = blockIdx.x*128, colBase = blockIdx.y*128;
    int tid = threadIdx.x, tx = tid & 15, ty = tid >> 4;
    float acc[8][8] = {};
    for (int k0 = 0; k0 < K; k0 += KC) {
        #pragma unroll
        for (int l = 0; l < 4; l++) {
            int id = tid + l*256;
            int kk = id & 7, r = id >> 3;   // r in 0..127
            float av = 0.f, bv = 0.f;
            if (k0 + kk < K) {
                av = Ab[(long)(rowBase + r)*lda + k0 + kk];
                if (colBase + r < Nj)
                    bv = Bb[(long)(colBase + r)*ldb + k0 + kk];
            }
            As[kk][r] = av; Bs[kk][r] = bv;
        }
        __syncthreads();
        #pragma unroll
        for (int kk = 0; kk < KC; kk++) {
            float a[8], b[8];
            #pragma unroll
            for (int i = 0; i < 8; i++) a[i] = As[kk][ty*8 + i];
            #pragma unroll
            for (int j = 0; j < 8; j++) b[j] = Bs[kk][tx*8 + j];
            #pragma unroll
            for (int i = 0; i < 8; i++)
                #pragma unroll
                for (int j = 0; j < 8; j++)
                    acc[i][j] = fmaf(a[i], b[j], acc[i][j]);
        }
        __syncthreads();
    }
    const float* sqz = sq + (long)z*sqStride;  // only dereferenced in mode 2
    #pragma unroll
    for (int i = 0; i < 8; i++) {
        int r = rowBase + ty*8 + i;
        #pragma unroll
        for (int j = 0; j < 8; j++) {
            int c = colBase + tx*8 + j;
            if (c >= Nj) continue;
            long off = (long)r*ldc + c;
            float v = acc[i][j];
            if (mode == 0)      Cb[off] = v;
            else if (mode == 1) Cb[off] += v;
            else                Cb[off] = 2.f*v - sqz[r] - sqz[c];
        }
    }
}

// ---------------- top-20 per row (value desc, index asc ties) ----------------
__global__ __launch_bounds__(256) void k_topk20(const float* __restrict__ dist,
                                                int* __restrict__ idxOut, int rowOffset)
{
    __shared__ float lds[4][2048];
    int wave = threadIdx.x >> 6, lane = threadIdx.x & 63;
    int row = blockIdx.x*4 + wave;
    const float* dr = dist + (long)row*2048;
    float* L = lds[wave];
    for (int i = 0; i < 32; i++) L[i*64 + lane] = dr[i*64 + lane];
    __syncthreads();
    int* out = idxOut + (long)(rowOffset + row)*20;
    for (int it = 0; it < 20; it++) {
        float bv = -INFINITY; int bi = 0x7fffffff;
        for (int i = 0; i < 32; i++) {
            float v = L[i*64 + lane];
            if (v > bv) { bv = v; bi = i*64 + lane; }
        }
        #pragma unroll
        for (int s = 32; s > 0; s >>= 1) {
            float ov = __shfl_xor(bv, s);
            int   oi = __shfl_xor(bi, s);
            if (ov > bv || (ov == bv && oi < bi)) { bv = ov; bi = oi; }
        }
        if (lane == 0) out[it] = bi;
        if (lane == (bi & 63)) L[bi] = -INFINITY;
    }
}

// ---------------- Wd = W[:,C:] - W[:,:C] ----------------
__global__ __launch_bounds__(256) void k_wdiff(const float* __restrict__ W,
                                               float* __restrict__ Wd, int O, int C) {
    int i = blockIdx.x*256 + threadIdx.x;
    if (i >= O*C) return;
    int o = i / C, c = i % C;
    Wd[o*C + c] = W[(long)o*2*C + C + c] - W[(long)o*2*C + c];
}

// ---------------- BN stats over gathered edge features ----------------
__global__ __launch_bounds__(256) void k_edge_stats(
    const float* __restrict__ p, const float* __restrict__ q,
    const int* __restrict__ idx, float* __restrict__ sums, int O)
{
    int nsub = 256 / O;
    int o = threadIdx.x & (O - 1);
    int sub = threadIdx.x / O;
    int base = blockIdx.x * 64;
    float s = 0.f, s2 = 0.f;
    for (int i = sub; i < 64; i += nsub) {
        int pt = base + i;
        int b = pt >> 11;
        float qv = q[(long)pt*O + o];
        const int* ir = idx + (long)pt*20;
        for (int k = 0; k < 20; k++) {
            int m = ir[k];
            float h = p[((long)(b << 11) + m)*O + o] + qv;
            s += h; s2 = fmaf(h, h, s2);
        }
    }
    atomicAdd(&sums[o], s);
    atomicAdd(&sums[O + o], s2);
}

// ---------------- scale/shift from sums ----------------
__global__ __launch_bounds__(256) void k_bn_finalize(
    const float* __restrict__ sums, const float* __restrict__ g,
    const float* __restrict__ beta, float* __restrict__ ss, int O, float invCnt)
{
    int o = blockIdx.x*256 + threadIdx.x;
    if (o >= O) return;
    float mean = sums[o]*invCnt;
    float var  = sums[O + o]*invCnt - mean*mean;
    float sc = g[o] * rsqrtf(var + 1e-5f);
    ss[o] = sc;
    ss[O + o] = beta[o] - mean*sc;
}

// ---------------- fused BN + lrelu + max over k ----------------
__global__ __launch_bounds__(256) void k_edge_out(
    const float* __restrict__ p, const float* __restrict__ q,
    const int* __restrict__ idx, const float* __restrict__ ss,
    float* __restrict__ out, int O)
{
    int nsub = 256 / O;
    int o = threadIdx.x & (O - 1);
    int sub = threadIdx.x / O;
    int base = blockIdx.x * 64;
    float sc = ss[o], sh = ss[O + o];
    for (int i = sub; i < 64; i += nsub) {
        int pt = base + i;
        int b = pt >> 11;
        float qv = q[(long)pt*O + o];
        const int* ir = idx + (long)pt*20;
        float mx = -INFINITY;
        for (int k = 0; k < 20; k++) {
            int m = ir[k];
            float h = p[((long)(b << 11) + m)*O + o] + qv;
            float y = fmaf(h, sc, sh);
            y = LRELU(y);
            mx = fmaxf(mx, y);
        }
        out[(long)pt*O + o] = mx;
    }
}

// ---------------- h5 stats (count = 32768 per channel) ----------------
__global__ __launch_bounds__(256) void k_h5_stats(const float* __restrict__ h5,
                                                  float* __restrict__ sums) {
    int o = blockIdx.y*256 + threadIdx.x;   // grid.y = 4 -> 1024 channels
    int base = blockIdx.x * 256;            // grid.x = 128 point chunks
    float s = 0.f, s2 = 0.f;
    for (int i = 0; i < 256; i++) {
        float v = h5[(long)(base + i)*1024 + o];
        s += v; s2 = fmaf(v, v, s2);
    }
    atomicAdd(&sums[o], s);
    atomicAdd(&sums[1024 + o], s2);
}

// ---------------- BN+lrelu then max & mean over N ----------------
__global__ __launch_bounds__(256) void k_reduce_f(const float* __restrict__ h5,
                                                  const float* __restrict__ ss,
                                                  float* __restrict__ f) {
    int o = blockIdx.y*256 + threadIdx.x;
    int b = blockIdx.x;
    float sc = ss[o], sh = ss[1024 + o];
    float mx = -INFINITY, sm = 0.f;
    for (int n = 0; n < 2048; n++) {
        float v = h5[((long)(b*2048 + n))*1024 + o];
        float y = fmaf(v, sc, sh); y = LRELU(y);
        mx = fmaxf(mx, y); sm += y;
    }
    f[(long)b*2048 + o] = mx;
    f[(long)b*2048 + 1024 + o] = sm * (1.f/2048.f);
}

// ---------------- small FC matmul: Y[b,j] = X[b,:].W[j,:] + bias ----------------
__global__ __launch_bounds__(256) void k_fc_mm(const float* __restrict__ X,
                                               const float* __restrict__ W,
                                               const float* __restrict__ bias,
                                               float* __restrict__ Y,
                                               int Kdim, int Ncol) {
    int t = blockIdx.x*256 + threadIdx.x;
    if (t >= 16*Ncol) return;
    int b = t / Ncol, j = t % Ncol;
    const float* xr = X + (long)b*Kdim;
    const float* wr = W + (long)j*Kdim;
    float s = 0.f;
    for (int k = 0; k < Kdim; k++) s = fmaf(xr[k], wr[k], s);
    Y[t] = s + (bias ? bias[j] : 0.f);
}

// ---------------- BN over batch axis (16) + lrelu ----------------
__global__ __launch_bounds__(256) void k_bn_rows(const float* __restrict__ X,
                                                 const float* __restrict__ g,
                                                 const float* __restrict__ be,
                                                 float* __restrict__ Y, int Ncol) {
    int j = blockIdx.x*256 + threadIdx.x;
    if (j >= Ncol) return;
    float s = 0.f, s2 = 0.f;
    for (int b = 0; b < 16; b++) { float v = X[b*Ncol + j]; s += v; s2 = fmaf(v, v, s2); }
    float mean = s*(1.f/16.f);
    float var  = s2*(1.f/16.f) - mean*mean;
    float sc = g[j]*rsqrtf(var + 1e-5f);
    float sh = be[j] - mean*sc;
    for (int b = 0; b < 16; b++) {
        float v = fmaf(X[b*Ncol + j], sc, sh);
        Y[b*Ncol + j] = LRELU(v);
    }
}

extern "C" void kernel_launch(void* const* d_in, const int* in_sizes, int n_in,
                              void* d_out, int out_size, void* d_ws, size_t ws_size,
                              hipStream_t stream) {
    const float* data = (const float*)d_in[0];
    const float* W1 = (const float*)d_in[1];  const float* g1 = (const float*)d_in[2];  const float* b1 = (const float*)d_in[3];
    const float* W2 = (const float*)d_in[4];  const float* g2 = (const float*)d_in[5];  const float* b2 = (const float*)d_in[6];
    const float* W3 = (const float*)d_in[7];  const float* g3 = (const float*)d_in[8];  const float* b3 = (const float*)d_in[9];
    const float* W4 = (const float*)d_in[10]; const float* g4 = (const float*)d_in[11]; const float* b4 = (const float*)d_in[12];
    const float* W5 = (const float*)d_in[13]; const float* g5 = (const float*)d_in[14]; const float* b5 = (const float*)d_in[15];
    const float* fc1W = (const float*)d_in[16]; const float* bn1g = (const float*)d_in[17]; const float* bn1b = (const float*)d_in[18];
    const float* fc2W = (const float*)d_in[19]; const float* fc2b = (const float*)d_in[20];
    const float* bn2g = (const float*)d_in[21]; const float* bn2b = (const float*)d_in[22];
    const float* fc3W = (const float*)d_in[23]; const float* fc3b = (const float*)d_in[24];

    // Static device scratch (285 MB) — do not depend on ws_size.
    void* wsym = nullptr;
    hipGetSymbolAddress(&wsym, HIP_SYMBOL(g_ws));
    char* w = (char*)wsym;
    size_t off = 0;
    auto alloc = [&](size_t bytes) { void* r = w + off; off += (bytes + 255) & ~size_t(255); return r; };
    float* S   = (float*)alloc(134217728);      // dist (8 batches) / h5 (32768x1024) - same size, reused
    float* x0  = (float*)alloc(393216);
    float* d1  = (float*)alloc(8388608);
    float* d2  = (float*)alloc(8388608);
    float* d3  = (float*)alloc(16777216);
    float* d4  = (float*)alloc(33554432);
    float* p   = (float*)alloc(33554432);
    float* q   = (float*)alloc(33554432);
    int*   idxb= (int*)  alloc(2621440);
    float* sqb = (float*)alloc(131072);
    float* Wd  = (float*)alloc(131072);
    float* sums= (float*)alloc(8192);
    float* ssb = (float*)alloc(8192);
    float* f   = (float*)alloc(131072);
    float* t1  = (float*)alloc(32768);
    float* a1  = (float*)alloc(32768);
    float* t2  = (float*)alloc(16384);
    float* a2  = (float*)alloc(16384);
    (void)ws_size; (void)n_in; (void)in_sizes; (void)out_size; (void)d_ws;

    k_transpose_in<<<128, 256, 0, stream>>>(data, x0);

    auto layer = [&](const float* x, int C, int O, const float* W,
                     const float* g, const float* beta, float* out) {
        k_sqnorm<<<128, 256, 0, stream>>>(x, sqb, C);
        for (int ch = 0; ch < 2; ch++) {
            const float* xc = x + (long)ch*16384*C;
            k_gemm_nt<<<dim3(16,16,8), 256, 0, stream>>>(
                xc, C, (long)2048*C, xc, C, (long)2048*C,
                S, 2048, (long)2048*2048, C, 2048, 2, sqb + ch*16384, 2048);
            k_topk20<<<4096, 256, 0, stream>>>(S, idxb, ch*16384);
        }
        k_wdiff<<<(O*C + 255)/256, 256, 0, stream>>>(W, Wd, O, C);
        k_gemm_nt<<<dim3(256, (O+127)/128, 1), 256, 0, stream>>>(
            x, C, 0, W, 2*C, 0, p, O, 0, C, O, 0, nullptr, 0);
        k_gemm_nt<<<dim3(256, (O+127)/128, 1), 256, 0, stream>>>(
            x, C, 0, Wd, C, 0, q, O, 0, C, O, 0, nullptr, 0);
        hipMemsetAsync(sums, 0, 2*O*sizeof(float), stream);
        k_edge_stats<<<512, 256, 0, stream>>>(p, q, idxb, sums, O);
        k_bn_finalize<<<(O+255)/256, 256, 0, stream>>>(sums, g, beta, ssb, O, 1.f/655360.f);
        k_edge_out<<<512, 256, 0, stream>>>(p, q, idxb, ssb, out, O);
    };

    layer(x0, 3,   64,  W1, g1, b1, d1);
    layer(d1, 64,  64,  W2, g2, b2, d2);
    layer(d2, 64,  128, W3, g3, b3, d3);
    layer(d3, 128, 256, W4, g4, b4, d4);

    // h5 = cat(d1,d2,d3,d4) @ W5^T  as 4 accumulating GEMMs into S
    k_gemm_nt<<<dim3(256,8,1), 256, 0, stream>>>(d1, 64,  0, W5 + 0,   512, 0, S, 1024, 0, 64,  1024, 0, nullptr, 0);
    k_gemm_nt<<<dim3(256,8,1), 256, 0, stream>>>(d2, 64,  0, W5 + 64,  512, 0, S, 1024, 0, 64,  1024, 1, nullptr, 0);
    k_gemm_nt<<<dim3(256,8,1), 256, 0, stream>>>(d3, 128, 0, W5 + 128, 512, 0, S, 1024, 0, 128, 1024, 1, nullptr, 0);
    k_gemm_nt<<<dim3(256,8,1), 256, 0, stream>>>(d4, 256, 0, W5 + 256, 512, 0, S, 1024, 0, 256, 1024, 1, nullptr, 0);

    hipMemsetAsync(sums, 0, 2*1024*sizeof(float), stream);
    k_h5_stats<<<dim3(128,4), 256, 0, stream>>>(S, sums);
    k_bn_finalize<<<4, 256, 0, stream>>>(sums, g5, b5, ssb, 1024, 1.f/32768.f);
    k_reduce_f<<<dim3(16,4), 256, 0, stream>>>(S, ssb, f);

    k_fc_mm<<<32, 256, 0, stream>>>(f,  fc1W, nullptr, t1, 2048, 512);
    k_bn_rows<<<2, 256, 0, stream>>>(t1, bn1g, bn1b, a1, 512);
    k_fc_mm<<<16, 256, 0, stream>>>(a1, fc2W, fc2b, t2, 512, 256);
    k_bn_rows<<<1, 256, 0, stream>>>(t2, bn2g, bn2b, a2, 256);
    k_fc_mm<<<3, 256, 0, stream>>>(a2, fc3W, fc3b, (float*)d_out, 256, 40);
}

// Round 3
// 3967.921 us; speedup vs baseline: 1.4341x; 1.4341x over previous
//
#include <hip/hip_runtime.h>
#include <math.h>

#define LRELU(x) ((x) >= 0.f ? (x) : 0.2f*(x))

// ---- static device scratch (285 MB): independent of harness ws_size ----
#define WS_FLOATS 71303168u
__device__ __align__(256) float g_ws[WS_FLOATS];

// ---------------- transpose (B,3,N) -> (B*N,3) ----------------
__global__ __launch_bounds__(256) void k_transpose_in(const float* __restrict__ data,
                                                      float* __restrict__ x0) {
    int i = blockIdx.x*256 + threadIdx.x;      // over B*N = 32768
    int b = i >> 11, n = i & 2047;
    #pragma unroll
    for (int c = 0; c < 3; c++)
        x0[(long)i*3 + c] = data[((long)b*3 + c)*2048 + n];
}

// ---------------- squared norms ----------------
__global__ __launch_bounds__(256) void k_sqnorm(const float* __restrict__ x,
                                                float* __restrict__ sq, int C) {
    int i = blockIdx.x*256 + threadIdx.x;      // over 32768 points
    const float* xr = x + (long)i*C;
    float s = 0.f;
    for (int c = 0; c < C; c++) s = fmaf(xr[c], xr[c], s);
    sq[i] = s;
}

// ---------------- fp32 GEMM: C[i,j] = sum_k A[i,k]*B[j,k] ----------------
// mode 0: store; mode 2: dist epilogue 2*acc - sq[i] - sq[j]
#define KC 8
__global__ __launch_bounds__(256) void k_gemm_nt(
    const float* __restrict__ A, int lda, long sAb,
    const float* __restrict__ B, int ldb, long sBb,
    float* __restrict__ Cm, int ldc, long sCb,
    int K, int Nj, int mode, const float* __restrict__ sq, int sqStride)
{
    __shared__ float As[KC][132];
    __shared__ float Bs[KC][132];
    int z = blockIdx.z;
    const float* Ab = A + (long)z*sAb;
    const float* Bb = B + (long)z*sBb;
    float* Cb = Cm + (long)z*sCb;
    int rowBase = blockIdx.x*128, colBase = blockIdx.y*128;
    int tid = threadIdx.x, tx = tid & 15, ty = tid >> 4;
    float acc[8][8] = {};
    for (int k0 = 0; k0 < K; k0 += KC) {
        #pragma unroll
        for (int l = 0; l < 4; l++) {
            int id = tid + l*256;
            int kk = id & 7, r = id >> 3;   // r in 0..127
            float av = 0.f, bv = 0.f;
            if (k0 + kk < K) {
                av = Ab[(long)(rowBase + r)*lda + k0 + kk];
                if (colBase + r < Nj)
                    bv = Bb[(long)(colBase + r)*ldb + k0 + kk];
            }
            As[kk][r] = av; Bs[kk][r] = bv;
        }
        __syncthreads();
        #pragma unroll
        for (int kk = 0; kk < KC; kk++) {
            float4 a0 = *(const float4*)&As[kk][ty*8];
            float4 a1 = *(const float4*)&As[kk][ty*8 + 4];
            float4 b0 = *(const float4*)&Bs[kk][tx*8];
            float4 b1 = *(const float4*)&Bs[kk][tx*8 + 4];
            float a[8] = {a0.x,a0.y,a0.z,a0.w,a1.x,a1.y,a1.z,a1.w};
            float b[8] = {b0.x,b0.y,b0.z,b0.w,b1.x,b1.y,b1.z,b1.w};
            #pragma unroll
            for (int i = 0; i < 8; i++)
                #pragma unroll
                for (int j = 0; j < 8; j++)
                    acc[i][j] = fmaf(a[i], b[j], acc[i][j]);
        }
        __syncthreads();
    }
    const float* sqz = sq + (long)z*sqStride;  // only dereferenced in mode 2
    #pragma unroll
    for (int i = 0; i < 8; i++) {
        int r = rowBase + ty*8 + i;
        float sqr = (mode == 2) ? sqz[r] : 0.f;
        #pragma unroll
        for (int jj = 0; jj < 8; jj += 4) {
            int c = colBase + tx*8 + jj;
            if (c + 3 < Nj) {
                float4 v;
                v.x = acc[i][jj+0]; v.y = acc[i][jj+1];
                v.z = acc[i][jj+2]; v.w = acc[i][jj+3];
                if (mode == 2) {
                    v.x = 2.f*v.x - sqr - sqz[c+0];
                    v.y = 2.f*v.y - sqr - sqz[c+1];
                    v.z = 2.f*v.z - sqr - sqz[c+2];
                    v.w = 2.f*v.w - sqr - sqz[c+3];
                }
                *(float4*)&Cb[(long)r*ldc + c] = v;
            } else {
                #pragma unroll
                for (int j = jj; j < jj+4; j++) {
                    int c2 = colBase + tx*8 + j;
                    if (c2 >= Nj) continue;
                    float v = acc[i][j];
                    if (mode == 2) v = 2.f*v - sqr - sqz[c2];
                    Cb[(long)r*ldc + c2] = v;
                }
            }
        }
    }
}

// ---------------- fused cat(d1,d2,d3,d4) @ W5^T   (K=512, out 32768x1024) ----------------
__global__ __launch_bounds__(256) void k_gemm_cat(
    const float* __restrict__ d1, const float* __restrict__ d2,
    const float* __restrict__ d3, const float* __restrict__ d4,
    const float* __restrict__ W5, float* __restrict__ Cm)
{
    __shared__ float As[KC][132];
    __shared__ float Bs[KC][132];
    int rowBase = blockIdx.x*128, colBase = blockIdx.y*128;
    int tid = threadIdx.x, tx = tid & 15, ty = tid >> 4;
    float acc[8][8] = {};
    for (int k0 = 0; k0 < 512; k0 += KC) {
        const float* Ab; int lda_, koff;
        if (k0 < 64)       { Ab = d1; lda_ = 64;  koff = k0; }
        else if (k0 < 128) { Ab = d2; lda_ = 64;  koff = k0 - 64; }
        else if (k0 < 256) { Ab = d3; lda_ = 128; koff = k0 - 128; }
        else               { Ab = d4; lda_ = 256; koff = k0 - 256; }
        #pragma unroll
        for (int l = 0; l < 4; l++) {
            int id = tid + l*256;
            int kk = id & 7, r = id >> 3;
            As[kk][r] = Ab[(long)(rowBase + r)*lda_ + koff + kk];
            Bs[kk][r] = W5[(long)(colBase + r)*512 + k0 + kk];
        }
        __syncthreads();
        #pragma unroll
        for (int kk = 0; kk < KC; kk++) {
            float4 a0 = *(const float4*)&As[kk][ty*8];
            float4 a1 = *(const float4*)&As[kk][ty*8 + 4];
            float4 b0 = *(const float4*)&Bs[kk][tx*8];
            float4 b1 = *(const float4*)&Bs[kk][tx*8 + 4];
            float a[8] = {a0.x,a0.y,a0.z,a0.w,a1.x,a1.y,a1.z,a1.w};
            float b[8] = {b0.x,b0.y,b0.z,b0.w,b1.x,b1.y,b1.z,b1.w};
            #pragma unroll
            for (int i = 0; i < 8; i++)
                #pragma unroll
                for (int j = 0; j < 8; j++)
                    acc[i][j] = fmaf(a[i], b[j], acc[i][j]);
        }
        __syncthreads();
    }
    #pragma unroll
    for (int i = 0; i < 8; i++) {
        long r = rowBase + ty*8 + i;
        #pragma unroll
        for (int jj = 0; jj < 8; jj += 4) {
            int c = colBase + tx*8 + jj;
            float4 v;
            v.x = acc[i][jj+0]; v.y = acc[i][jj+1];
            v.z = acc[i][jj+2]; v.w = acc[i][jj+3];
            *(float4*)&Cm[r*1024 + c] = v;
        }
    }
}

// ---------------- top-20 per row (value desc, index asc ties) ----------------
__global__ __launch_bounds__(256) void k_topk20(const float* __restrict__ dist,
                                                int* __restrict__ idxOut, int rowOffset)
{
    __shared__ float lds[4][2048];
    int wave = threadIdx.x >> 6, lane = threadIdx.x & 63;
    int row = blockIdx.x*4 + wave;
    const float* dr = dist + (long)row*2048;
    float* L = lds[wave];
    for (int i = 0; i < 32; i++) L[i*64 + lane] = dr[i*64 + lane];
    __syncthreads();
    int* out = idxOut + (long)(rowOffset + row)*20;
    for (int it = 0; it < 20; it++) {
        float bv = -INFINITY; int bi = 0x7fffffff;
        for (int i = 0; i < 32; i++) {
            float v = L[i*64 + lane];
            if (v > bv) { bv = v; bi = i*64 + lane; }
        }
        #pragma unroll
        for (int s = 32; s > 0; s >>= 1) {
            float ov = __shfl_xor(bv, s);
            int   oi = __shfl_xor(bi, s);
            if (ov > bv || (ov == bv && oi < bi)) { bv = ov; bi = oi; }
        }
        if (lane == 0) out[it] = bi;
        if (lane == (bi & 63)) L[bi] = -INFINITY;
    }
}

// ---------------- Wd = W[:,C:] - W[:,:C] ----------------
__global__ __launch_bounds__(256) void k_wdiff(const float* __restrict__ W,
                                               float* __restrict__ Wd, int O, int C) {
    int i = blockIdx.x*256 + threadIdx.x;
    if (i >= O*C) return;
    int o = i / C, c = i % C;
    Wd[o*C + c] = W[(long)o*2*C + C + c] - W[(long)o*2*C + c];
}

// ---------------- BN stats over gathered edge features ----------------
__global__ __launch_bounds__(256) void k_edge_stats(
    const float* __restrict__ p, const float* __restrict__ q,
    const int* __restrict__ idx, float* __restrict__ sums, int O)
{
    int nsub = 256 / O;
    int o = threadIdx.x & (O - 1);
    int sub = threadIdx.x / O;
    int base = blockIdx.x * 64;
    float s = 0.f, s2 = 0.f;
    for (int i = sub; i < 64; i += nsub) {
        int pt = base + i;
        int b = pt >> 11;
        float qv = q[(long)pt*O + o];
        const int* ir = idx + (long)pt*20;
        for (int k = 0; k < 20; k++) {
            int m = ir[k];
            float h = p[((long)(b << 11) + m)*O + o] + qv;
            s += h; s2 = fmaf(h, h, s2);
        }
    }
    atomicAdd(&sums[o], s);
    atomicAdd(&sums[O + o], s2);
}

// ---------------- scale/shift from sums ----------------
__global__ __launch_bounds__(256) void k_bn_finalize(
    const float* __restrict__ sums, const float* __restrict__ g,
    const float* __restrict__ beta, float* __restrict__ ss, int O, float invCnt)
{
    int o = blockIdx.x*256 + threadIdx.x;
    if (o >= O) return;
    float mean = sums[o]*invCnt;
    float var  = sums[O + o]*invCnt - mean*mean;
    float sc = g[o] * rsqrtf(var + 1e-5f);
    ss[o] = sc;
    ss[O + o] = beta[o] - mean*sc;
}

// ---------------- fused BN + lrelu + max over k ----------------
__global__ __launch_bounds__(256) void k_edge_out(
    const float* __restrict__ p, const float* __restrict__ q,
    const int* __restrict__ idx, const float* __restrict__ ss,
    float* __restrict__ out, int O)
{
    int nsub = 256 / O;
    int o = threadIdx.x & (O - 1);
    int sub = threadIdx.x / O;
    int base = blockIdx.x * 64;
    float sc = ss[o], sh = ss[O + o];
    for (int i = sub; i < 64; i += nsub) {
        int pt = base + i;
        int b = pt >> 11;
        float qv = q[(long)pt*O + o];
        const int* ir = idx + (long)pt*20;
        float mx = -INFINITY;
        for (int k = 0; k < 20; k++) {
            int m = ir[k];
            float h = p[((long)(b << 11) + m)*O + o] + qv;
            float y = fmaf(h, sc, sh);
            y = LRELU(y);
            mx = fmaxf(mx, y);
        }
        out[(long)pt*O + o] = mx;
    }
}

// ---------------- h5 stats (count = 32768 per channel) ----------------
__global__ __launch_bounds__(256) void k_h5_stats(const float* __restrict__ h5,
                                                  float* __restrict__ sums) {
    int o = blockIdx.y*256 + threadIdx.x;   // grid.y = 4 -> 1024 channels
    int base = blockIdx.x * 256;            // grid.x = 128 point chunks
    float s = 0.f, s2 = 0.f;
    for (int i = 0; i < 256; i++) {
        float v = h5[(long)(base + i)*1024 + o];
        s += v; s2 = fmaf(v, v, s2);
    }
    atomicAdd(&sums[o], s);
    atomicAdd(&sums[1024 + o], s2);
}

// ---------------- BN+lrelu then max & mean over N ----------------
__global__ __launch_bounds__(256) void k_reduce_f(const float* __restrict__ h5,
                                                  const float* __restrict__ ss,
                                                  float* __restrict__ f) {
    int o = blockIdx.y*256 + threadIdx.x;
    int b = blockIdx.x;
    float sc = ss[o], sh = ss[1024 + o];
    float mx = -INFINITY, sm = 0.f;
    for (int n = 0; n < 2048; n++) {
        float v = h5[((long)(b*2048 + n))*1024 + o];
        float y = fmaf(v, sc, sh); y = LRELU(y);
        mx = fmaxf(mx, y); sm += y;
    }
    f[(long)b*2048 + o] = mx;
    f[(long)b*2048 + 1024 + o] = sm * (1.f/2048.f);
}

// ---------------- small FC matmul: Y[b,j] = X[b,:].W[j,:] + bias ----------------
__global__ __launch_bounds__(256) void k_fc_mm(const float* __restrict__ X,
                                               const float* __restrict__ W,
                                               const float* __restrict__ bias,
                                               float* __restrict__ Y,
                                               int Kdim, int Ncol) {
    int t = blockIdx.x*256 + threadIdx.x;
    if (t >= 16*Ncol) return;
    int b = t / Ncol, j = t % Ncol;
    const float* xr = X + (long)b*Kdim;
    const float* wr = W + (long)j*Kdim;
    float s = 0.f;
    for (int k = 0; k < Kdim; k++) s = fmaf(xr[k], wr[k], s);
    Y[t] = s + (bias ? bias[j] : 0.f);
}

// ---------------- BN over batch axis (16) + lrelu ----------------
__global__ __launch_bounds__(256) void k_bn_rows(const float* __restrict__ X,
                                                 const float* __restrict__ g,
                                                 const float* __restrict__ be,
                                                 float* __restrict__ Y, int Ncol) {
    int j = blockIdx.x*256 + threadIdx.x;
    if (j >= Ncol) return;
    float s = 0.f, s2 = 0.f;
    for (int b = 0; b < 16; b++) { float v = X[b*Ncol + j]; s += v; s2 = fmaf(v, v, s2); }
    float mean = s*(1.f/16.f);
    float var  = s2*(1.f/16.f) - mean*mean;
    float sc = g[j]*rsqrtf(var + 1e-5f);
    float sh = be[j] - mean*sc;
    for (int b = 0; b < 16; b++) {
        float v = fmaf(X[b*Ncol + j], sc, sh);
        Y[b*Ncol + j] = LRELU(v);
    }
}

extern "C" void kernel_launch(void* const* d_in, const int* in_sizes, int n_in,
                              void* d_out, int out_size, void* d_ws, size_t ws_size,
                              hipStream_t stream) {
    const float* data = (const float*)d_in[0];
    const float* W1 = (const float*)d_in[1];  const float* g1 = (const float*)d_in[2];  const float* b1 = (const float*)d_in[3];
    const float* W2 = (const float*)d_in[4];  const float* g2 = (const float*)d_in[5];  const float* b2 = (const float*)d_in[6];
    const float* W3 = (const float*)d_in[7];  const float* g3 = (const float*)d_in[8];  const float* b3 = (const float*)d_in[9];
    const float* W4 = (const float*)d_in[10]; const float* g4 = (const float*)d_in[11]; const float* b4 = (const float*)d_in[12];
    const float* W5 = (const float*)d_in[13]; const float* g5 = (const float*)d_in[14]; const float* b5 = (const float*)d_in[15];
    const float* fc1W = (const float*)d_in[16]; const float* bn1g = (const float*)d_in[17]; const float* bn1b = (const float*)d_in[18];
    const float* fc2W = (const float*)d_in[19]; const float* fc2b = (const float*)d_in[20];
    const float* bn2g = (const float*)d_in[21]; const float* bn2b = (const float*)d_in[22];
    const float* fc3W = (const float*)d_in[23]; const float* fc3b = (const float*)d_in[24];

    void* wsym = nullptr;
    hipGetSymbolAddress(&wsym, HIP_SYMBOL(g_ws));
    char* w = (char*)wsym;
    size_t off = 0;
    auto alloc = [&](size_t bytes) { void* r = w + off; off += (bytes + 255) & ~size_t(255); return r; };
    float* S   = (float*)alloc(134217728);      // dist (8 batches) / h5 (32768x1024) - reused
    float* x0  = (float*)alloc(393216);
    float* d1  = (float*)alloc(8388608);
    float* d2  = (float*)alloc(8388608);
    float* d3  = (float*)alloc(16777216);
    float* d4  = (float*)alloc(33554432);
    float* p   = (float*)alloc(33554432);
    float* q   = (float*)alloc(33554432);
    int*   idxb= (int*)  alloc(2621440);
    float* sqb = (float*)alloc(131072);
    float* Wd  = (float*)alloc(131072);
    float* sums= (float*)alloc(8192);
    float* ssb = (float*)alloc(8192);
    float* f   = (float*)alloc(131072);
    float* t1  = (float*)alloc(32768);
    float* a1  = (float*)alloc(32768);
    float* t2  = (float*)alloc(16384);
    float* a2  = (float*)alloc(16384);
    (void)ws_size; (void)n_in; (void)in_sizes; (void)out_size; (void)d_ws;

    k_transpose_in<<<128, 256, 0, stream>>>(data, x0);

    auto layer = [&](const float* x, int C, int O, const float* W,
                     const float* g, const float* beta, float* out) {
        k_sqnorm<<<128, 256, 0, stream>>>(x, sqb, C);
        for (int ch = 0; ch < 2; ch++) {
            const float* xc = x + (long)ch*16384*C;
            k_gemm_nt<<<dim3(16,16,8), 256, 0, stream>>>(
                xc, C, (long)2048*C, xc, C, (long)2048*C,
                S, 2048, (long)2048*2048, C, 2048, 2, sqb + ch*16384, 2048);
            k_topk20<<<4096, 256, 0, stream>>>(S, idxb, ch*16384);
        }
        k_wdiff<<<(O*C + 255)/256, 256, 0, stream>>>(W, Wd, O, C);
        k_gemm_nt<<<dim3(256, (O+127)/128, 1), 256, 0, stream>>>(
            x, C, 0, W, 2*C, 0, p, O, 0, C, O, 0, nullptr, 0);
        k_gemm_nt<<<dim3(256, (O+127)/128, 1), 256, 0, stream>>>(
            x, C, 0, Wd, C, 0, q, O, 0, C, O, 0, nullptr, 0);
        hipMemsetAsync(sums, 0, 2*O*sizeof(float), stream);
        k_edge_stats<<<512, 256, 0, stream>>>(p, q, idxb, sums, O);
        k_bn_finalize<<<(O+255)/256, 256, 0, stream>>>(sums, g, beta, ssb, O, 1.f/655360.f);
        k_edge_out<<<512, 256, 0, stream>>>(p, q, idxb, ssb, out, O);
    };

    layer(x0, 3,   64,  W1, g1, b1, d1);
    layer(d1, 64,  64,  W2, g2, b2, d2);
    layer(d2, 64,  128, W3, g3, b3, d3);
    layer(d3, 128, 256, W4, g4, b4, d4);

    // fused h5 = cat(d1,d2,d3,d4) @ W5^T
    k_gemm_cat<<<dim3(256,8,1), 256, 0, stream>>>(d1, d2, d3, d4, W5, S);

    hipMemsetAsync(sums, 0, 2*1024*sizeof(float), stream);
    k_h5_stats<<<dim3(128,4), 256, 0, stream>>>(S, sums);
    k_bn_finalize<<<4, 256, 0, stream>>>(sums, g5, b5, ssb, 1024, 1.f/32768.f);
    k_reduce_f<<<dim3(16,4), 256, 0, stream>>>(S, ssb, f);

    k_fc_mm<<<32, 256, 0, stream>>>(f,  fc1W, nullptr, t1, 2048, 512);
    k_bn_rows<<<2, 256, 0, stream>>>(t1, bn1g, bn1b, a1, 512);
    k_fc_mm<<<16, 256, 0, stream>>>(a1, fc2W, fc2b, t2, 512, 256);
    k_bn_rows<<<1, 256, 0, stream>>>(t2, bn2g, bn2b, a2, 256);
    k_fc_mm<<<3, 256, 0, stream>>>(a2, fc3W, fc3b, (float*)d_out, 256, 40);
}